// Round 2
// baseline (213.387 us; speedup 1.0000x reference)
//
#include <hip/hip_runtime.h>
#include <stdint.h>

typedef unsigned short u16;
typedef unsigned int u32;
typedef __attribute__((ext_vector_type(8))) short short8;
typedef __attribute__((ext_vector_type(4))) float f32x4;

#define B_    8
#define N_    4096
#define DIM_  256
#define HD_   2048
#define NQKV_ 4096

__device__ __forceinline__ float bf2f(u16 u) {
  union { u32 u; float f; } v; v.u = ((u32)u) << 16; return v.f;
}
__device__ __forceinline__ u16 f2bf(float f) {
  union { float f; u32 u; } v; v.f = f;
  u32 r = v.u + 0x7fffu + ((v.u >> 16) & 1u);
  return (u16)(r >> 16);
}
// dual-dtype input load: isbf ? bf16[i] : f32[i]
__device__ __forceinline__ float ldin(const void* p, size_t i, int isbf) {
  return isbf ? bf2f(((const u16*)p)[i]) : ((const float*)p)[i];
}
__device__ __forceinline__ void load16_to_lds(const u16* gsrc, u16* ldst) {
  auto gp = (const __attribute__((address_space(1))) void*)(uintptr_t)gsrc;
  auto lp = (__attribute__((address_space(3))) void*)(uintptr_t)ldst;
  __builtin_amdgcn_global_load_lds(gp, lp, 16, 0, 0);
}

// ---- dtype probe: bf16 data => low u16 of each u32 has plausible bf16 exponent ----
__global__ void probe_kernel(const void* x, int* flag) {
  __shared__ int cnt;
  if (threadIdx.x == 0) cnt = 0;
  __syncthreads();
  u32 w = ((const u32*)x)[threadIdx.x];
  int e = (int)((w >> 7) & 0xff);
  if (e >= 118 && e <= 130) atomicAdd(&cnt, 1);
  __syncthreads();
  if (threadIdx.x == 0) *flag = (cnt >= 128) ? 1 : 0;
}

// ---- x -> bf16 copy/convert (8 elems/thread) ----
__global__ void cvt_x_kernel(const void* __restrict__ x, u16* __restrict__ xb,
                             const int* __restrict__ flag) {
  int isbf = *flag;
  size_t i = (size_t)blockIdx.x * 256 + threadIdx.x;  // 1048576 total
  if (isbf) {
    ((short8*)xb)[i] = ((const short8*)x)[i];
  } else {
    const f32x4* xp = (const f32x4*)x + i * 2;
    f32x4 a = xp[0], b = xp[1];
    short8 o;
    o[0] = (short)f2bf(a[0]); o[1] = (short)f2bf(a[1]);
    o[2] = (short)f2bf(a[2]); o[3] = (short)f2bf(a[3]);
    o[4] = (short)f2bf(b[0]); o[5] = (short)f2bf(b[1]);
    o[6] = (short)f2bf(b[2]); o[7] = (short)f2bf(b[3]);
    ((short8*)xb)[i] = o;
  }
}

// ---- w2t[c][k] = bf16(qkv_w[k][2048+c]); c 0..2047, k 0..255 ----
__global__ void tr_w2t_kernel(const void* __restrict__ qkv_w, u16* __restrict__ w2t,
                              const int* __restrict__ flag) {
  int isbf = *flag;
  __shared__ float tile[32][33];
  int tx = threadIdx.x, ty = threadIdx.y;
  int c0 = blockIdx.x * 32, k0 = blockIdx.y * 32;
  for (int i = ty; i < 32; i += 8)
    tile[i][tx] = ldin(qkv_w, (size_t)(k0 + i) * NQKV_ + HD_ + c0 + tx, isbf);
  __syncthreads();
  for (int i = ty; i < 32; i += 8)
    w2t[(size_t)(c0 + i) * 256 + k0 + tx] = f2bf(tile[tx][i]);
}

// ---- pt[c][e] = bf16(proj_w[e][c]); c 0..255, e 0..2047 ----
__global__ void tr_pt_kernel(const void* __restrict__ proj_w, u16* __restrict__ pt,
                             const int* __restrict__ flag) {
  int isbf = *flag;
  __shared__ float tile[32][33];
  int tx = threadIdx.x, ty = threadIdx.y;
  int c0 = blockIdx.x * 32, e0 = blockIdx.y * 32;
  for (int i = ty; i < 32; i += 8)
    tile[i][tx] = ldin(proj_w, (size_t)(e0 + i) * 256 + c0 + tx, isbf);
  __syncthreads();
  for (int i = ty; i < 32; i += 8)
    pt[(size_t)(c0 + i) * HD_ + e0 + tx] = f2bf(tile[tx][i]);
}

// ---- xsum[b][k] = sum_n x[b,n,k], deterministic two-stage ----
__global__ void colsum1_kernel(const void* __restrict__ x, float* __restrict__ part,
                               const int* __restrict__ flag) {
  int isbf = *flag;
  int b = blockIdx.x >> 4, chunk = blockIdx.x & 15, k = threadIdx.x;
  size_t base = ((size_t)b * N_ + (size_t)chunk * 256) * DIM_ + k;
  float s = 0.f;
  for (int n = 0; n < 256; ++n) s += ldin(x, base + (size_t)n * DIM_, isbf);
  part[(b * 16 + chunk) * DIM_ + k] = s;
}
__global__ void colsum2_kernel(const float* __restrict__ part, float* __restrict__ xsum) {
  int b = blockIdx.x, k = threadIdx.x;
  float s = 0.f;
  for (int c = 0; c < 16; ++c) s += part[(b * 16 + c) * DIM_ + k];
  xsum[b * DIM_ + k] = s;
}

// ---- biases -> fp32 in ws ----
__global__ void cvt_bias_kernel(const void* __restrict__ qkv_b, const void* __restrict__ proj_b,
                                float* __restrict__ qb, float* __restrict__ pbv,
                                const int* __restrict__ flag) {
  int isbf = *flag;
  int i = blockIdx.x * 256 + threadIdx.x;
  if (i < NQKV_) qb[i] = ldin(qkv_b, i, isbf);
  else if (i < NQKV_ + DIM_) pbv[i - NQKV_] = ldin(proj_b, i - NQKV_, isbf);
}

// ---- g[b][hd] = scale * (xsum[b]·qkv_w[:,hd] + N*qkv_b[hd]) * sum_r lunchbox[d][r] ----
__global__ void g_kernel(const float* __restrict__ xsum, const void* __restrict__ qkv_w,
                         const float* __restrict__ qb, const void* __restrict__ lunchbox,
                         float* __restrict__ g, const int* __restrict__ flag) {
  int isbf = *flag;
  int idx = blockIdx.x * 256 + threadIdx.x;  // 16384 = B*HD
  int b = idx >> 11, hd = idx & 2047, d = hd & 255;
  const float* xs = xsum + b * DIM_;
  float s = 0.f;
  for (int k = 0; k < DIM_; ++k) s += xs[k] * ldin(qkv_w, (size_t)k * NQKV_ + hd, isbf);
  s += 4096.0f * qb[hd];
  float L = 0.f;
  for (int r = 0; r < 32; ++r) L += ldin(lunchbox, d * 32 + r, isbf);
  g[idx] = 0.0625f * s * L;  // scale = max(256,32)^-0.5
}

// ---- fused: per (b,h,q): out[128x256] = sum_j (G ∘ (Xj @ W2h)) @ Pj ----
__global__ __launch_bounds__(512) void fused_kernel(
    const u16* __restrict__ xb, const u16* __restrict__ w2t, const u16* __restrict__ pt,
    const float* __restrict__ qb, const float* __restrict__ g,
    const float* __restrict__ pbv, void* __restrict__ outv, const int* __restrict__ flag)
{
  __shared__ alignas(16) u16 smem[28672];  // 56 KB
  u16* sA = smem;                // [128][32] bf16 (8 KB)   - X tile
  u16* sB = smem + 4096;         // [256][32] bf16 (16 KB)  - W2h/pt tile
  u16* sT = smem + 12288;        // 4 x [128][32] (32 KB)   - scaled V chunk
  float* eps = (float*)(smem + 12288);  // 32x256 f32 epilogue staging (aliases sT)

  const int t = threadIdx.x, lane = t & 63, wave = t >> 6;
  const int wr = wave >> 2, wc = wave & 3;           // 2 x 4 wave grid
  const int blk = blockIdx.x;
  const int q = blk & 3, h = (blk >> 2) & 7, b = blk >> 5;
  const u16* xB = xb + ((size_t)b * N_ + (size_t)q * 1024) * DIM_;
  const u16* w2h = w2t + (size_t)h * 256 * 256;
  const int koff = (lane >> 4) * 8;

  f32x4 accB[4][4] = {};

  for (int j = 0; j < 8; ++j) {
    for (int dh = 0; dh < 2; ++dh) {
      // ---- GEMM-A: V[128][128] = Xj[128x256] @ W2h[256 x 128(dh half)] ----
      f32x4 accA[4][2] = {};
      for (int ks = 0; ks < 8; ++ks) {
        {
          int o = t * 16, row = o >> 6, kb = (o & 63) >> 1;
          load16_to_lds(xB + (size_t)(8 * row + j) * DIM_ + ks * 32 + kb, sA + (o >> 1));
        }
        {
          int o = t * 16, col = o >> 6, kb = (o & 63) >> 1;
          load16_to_lds(w2h + (size_t)(dh * 128 + col) * 256 + ks * 32 + kb, sB + (o >> 1));
        }
        __syncthreads();
        short8 af[4], bfr[2];
        const int ar = wr * 64 + (lane & 15);
#pragma unroll
        for (int mi = 0; mi < 4; ++mi)
          af[mi] = *(const short8*)&sA[(ar + mi * 16) * 32 + koff];
        const int bc = wc * 32 + (lane & 15);
#pragma unroll
        for (int ni = 0; ni < 2; ++ni)
          bfr[ni] = *(const short8*)&sB[(bc + ni * 16) * 32 + koff];
#pragma unroll
        for (int mi = 0; mi < 4; ++mi)
#pragma unroll
          for (int ni = 0; ni < 2; ++ni)
            accA[mi][ni] = __builtin_amdgcn_mfma_f32_16x16x32_bf16(af[mi], bfr[ni], accA[mi][ni], 0, 0, 0);
        __syncthreads();
      }
      // ---- scale by G, pack bf16 into sT [kk][128][32] ----
#pragma unroll
      for (int ni = 0; ni < 2; ++ni) {
        int dl = wc * 32 + ni * 16 + (lane & 15);    // 0..127
        int d = dh * 128 + dl;
        float gv = g[((size_t)b * 8 + h) * 256 + d];
        float bv = qb[HD_ + h * 256 + d];
        int kk = dl >> 5, ksub = dl & 31;
        u16* dst = sT + kk * 4096 + ksub;
#pragma unroll
        for (int mi = 0; mi < 4; ++mi) {
          f32x4 v = accA[mi][ni];
          int u0 = wr * 64 + mi * 16 + (lane >> 4) * 4;
          dst[(u0 + 0) * 32] = f2bf(gv * (v[0] + bv));
          dst[(u0 + 1) * 32] = f2bf(gv * (v[1] + bv));
          dst[(u0 + 2) * 32] = f2bf(gv * (v[2] + bv));
          dst[(u0 + 3) * 32] = f2bf(gv * (v[3] + bv));
        }
      }
      __syncthreads();
      // ---- GEMM-B: accB += T[128x128] @ proj_w[j*256+dh*128 .. +128][0..256] ----
      for (int ks = 0; ks < 4; ++ks) {
        {
          int o = t * 16, col = o >> 6, kb = (o & 63) >> 1;
          load16_to_lds(pt + (size_t)col * HD_ + j * 256 + dh * 128 + ks * 32 + kb, sB + (o >> 1));
        }
        {
          int o = (512 + t) * 16, col = o >> 6, kb = (o & 63) >> 1;
          load16_to_lds(pt + (size_t)col * HD_ + j * 256 + dh * 128 + ks * 32 + kb, sB + (o >> 1));
        }
        __syncthreads();
        short8 af2[4], bf2[4];
        const int ar2 = wr * 64 + (lane & 15);
        const u16* tsrc = sT + ks * 4096;
#pragma unroll
        for (int mi = 0; mi < 4; ++mi)
          af2[mi] = *(const short8*)&tsrc[(ar2 + mi * 16) * 32 + koff];
        const int bc2 = wc * 64 + (lane & 15);
#pragma unroll
        for (int ni = 0; ni < 4; ++ni)
          bf2[ni] = *(const short8*)&sB[(bc2 + ni * 16) * 32 + koff];
#pragma unroll
        for (int mi = 0; mi < 4; ++mi)
#pragma unroll
          for (int ni = 0; ni < 4; ++ni)
            accB[mi][ni] = __builtin_amdgcn_mfma_f32_16x16x32_bf16(af2[mi], bf2[ni], accB[mi][ni], 0, 0, 0);
        __syncthreads();
      }
    }
  }

  // ---- epilogue: + proj_b, store f32 or bf16 per flag ----
  int isbf = *flag;
  const int brow = (b * 8 + h) * 512 + q * 128;
  const int rl = t >> 4, cc = (t & 15) * 16;
  float pb[16];
#pragma unroll
  for (int ii = 0; ii < 16; ++ii) pb[ii] = pbv[cc + ii];
#pragma unroll
  for (int mi = 0; mi < 4; ++mi) {
    __syncthreads();
#pragma unroll
    for (int ni = 0; ni < 4; ++ni) {
      f32x4 v = accB[mi][ni];
      int r = wr * 16 + (lane >> 4) * 4, c = wc * 64 + ni * 16 + (lane & 15);
      eps[(r + 0) * 256 + c] = v[0];
      eps[(r + 1) * 256 + c] = v[1];
      eps[(r + 2) * 256 + c] = v[2];
      eps[(r + 3) * 256 + c] = v[3];
    }
    __syncthreads();
    int grow = brow + (rl >> 4) * 64 + mi * 16 + (rl & 15);
    if (isbf) {
      u16* op = (u16*)outv + (size_t)grow * 256 + cc;
      short8 o0, o1;
#pragma unroll
      for (int ii = 0; ii < 8; ++ii) o0[ii] = (short)f2bf(eps[rl * 256 + cc + ii] + pb[ii]);
#pragma unroll
      for (int ii = 0; ii < 8; ++ii) o1[ii] = (short)f2bf(eps[rl * 256 + cc + 8 + ii] + pb[8 + ii]);
      *(short8*)op = o0;
      *(short8*)(op + 8) = o1;
    } else {
      float* op = (float*)outv + (size_t)grow * 256 + cc;
#pragma unroll
      for (int ch = 0; ch < 4; ++ch) {
        f32x4 o_;
        o_[0] = eps[rl * 256 + cc + ch * 4 + 0] + pb[ch * 4 + 0];
        o_[1] = eps[rl * 256 + cc + ch * 4 + 1] + pb[ch * 4 + 1];
        o_[2] = eps[rl * 256 + cc + ch * 4 + 2] + pb[ch * 4 + 2];
        o_[3] = eps[rl * 256 + cc + ch * 4 + 3] + pb[ch * 4 + 3];
        ((f32x4*)op)[ch] = o_;
      }
    }
  }
}

extern "C" void kernel_launch(void* const* d_in, const int* in_sizes, int n_in,
                              void* d_out, int out_size, void* d_ws, size_t ws_size,
                              hipStream_t stream) {
  const void* x        = d_in[0];
  const void* qkv_w    = d_in[1];
  const void* qkv_b    = d_in[2];
  const void* lunchbox = d_in[3];
  const void* proj_w   = d_in[4];
  const void* proj_b   = d_in[5];
  char* ws = (char*)d_ws;

  // workspace layout (~18.2 MiB total)
  u16*   xbuf = (u16*)(ws + 0);           // 16 MiB
  u16*   w2t  = (u16*)(ws + 16777216);    // 1 MiB
  u16*   pt   = (u16*)(ws + 17825792);    // 1 MiB
  float* part = (float*)(ws + 18874368);  // 128 KiB
  float* xsum = (float*)(ws + 19005440);  // 8 KiB
  float* g    = (float*)(ws + 19013632);  // 64 KiB
  float* qb   = (float*)(ws + 19079168);  // 16 KiB
  float* pbv  = (float*)(ws + 19095552);  // 1 KiB
  int*   flag = (int*)(ws + 19096576);    // 4 B

  probe_kernel<<<1, 256, 0, stream>>>(x, flag);
  cvt_x_kernel<<<4096, 256, 0, stream>>>(x, xbuf, flag);
  tr_w2t_kernel<<<dim3(64, 8), dim3(32, 8), 0, stream>>>(qkv_w, w2t, flag);
  tr_pt_kernel<<<dim3(8, 64), dim3(32, 8), 0, stream>>>(proj_w, pt, flag);
  colsum1_kernel<<<128, 256, 0, stream>>>(x, part, flag);
  colsum2_kernel<<<8, 256, 0, stream>>>(part, xsum);
  cvt_bias_kernel<<<17, 256, 0, stream>>>(qkv_b, proj_b, qb, pbv, flag);
  g_kernel<<<64, 256, 0, stream>>>(xsum, qkv_w, qb, lunchbox, g, flag);

  fused_kernel<<<256, 512, 0, stream>>>(xbuf, w2t, pt, qb, g, pbv, d_out, flag);
}

// Round 3
// 176.886 us; speedup vs baseline: 1.2064x; 1.2064x over previous
//
#include <hip/hip_runtime.h>
#include <stdint.h>

typedef unsigned short u16;
typedef unsigned int u32;
typedef __attribute__((ext_vector_type(8))) short short8;
typedef __attribute__((ext_vector_type(4))) float f32x4;

#define B_    8
#define N_    4096
#define DIM_  256
#define HD_   2048
#define NQKV_ 4096

__device__ __forceinline__ float bf2f(u16 u) {
  union { u32 u; float f; } v; v.u = ((u32)u) << 16; return v.f;
}
__device__ __forceinline__ u16 f2bf(float f) {
  union { float f; u32 u; } v; v.f = f;
  u32 r = v.u + 0x7fffu + ((v.u >> 16) & 1u);
  return (u16)(r >> 16);
}
__device__ __forceinline__ float ldin(const void* p, size_t i, int isbf) {
  return isbf ? bf2f(((const u16*)p)[i]) : ((const float*)p)[i];
}
__device__ __forceinline__ void load16_to_lds(const u16* gsrc, u16* ldst) {
  auto gp = (const __attribute__((address_space(1))) void*)(uintptr_t)gsrc;
  auto lp = (__attribute__((address_space(3))) void*)(uintptr_t)ldst;
  __builtin_amdgcn_global_load_lds(gp, lp, 16, 0, 0);
}

// ---- dtype probe ----
__global__ void probe_kernel(const void* x, int* flag) {
  __shared__ int cnt;
  if (threadIdx.x == 0) cnt = 0;
  __syncthreads();
  u32 w = ((const u32*)x)[threadIdx.x];
  int e = (int)((w >> 7) & 0xff);
  if (e >= 118 && e <= 130) atomicAdd(&cnt, 1);
  __syncthreads();
  if (threadIdx.x == 0) *flag = (cnt >= 128) ? 1 : 0;
}

// ---- x -> bf16 (8 elems/thread) ----
__global__ void cvt_x_kernel(const void* __restrict__ x, u16* __restrict__ xb,
                             const int* __restrict__ flag) {
  int isbf = *flag;
  size_t i = (size_t)blockIdx.x * 256 + threadIdx.x;  // 1048576 total
  if (isbf) {
    ((short8*)xb)[i] = ((const short8*)x)[i];
  } else {
    const f32x4* xp = (const f32x4*)x + i * 2;
    f32x4 a = xp[0], b = xp[1];
    short8 o;
    o[0] = (short)f2bf(a[0]); o[1] = (short)f2bf(a[1]);
    o[2] = (short)f2bf(a[2]); o[3] = (short)f2bf(a[3]);
    o[4] = (short)f2bf(b[0]); o[5] = (short)f2bf(b[1]);
    o[6] = (short)f2bf(b[2]); o[7] = (short)f2bf(b[3]);
    ((short8*)xb)[i] = o;
  }
}

// ---- wv[k][e] = bf16(qkv_w[k][2048+e]),  256x2048 ----
__global__ void cvt_wv_kernel(const void* __restrict__ qkv_w, u16* __restrict__ wv,
                              const int* __restrict__ flag) {
  int isbf = *flag;
  size_t i = ((size_t)blockIdx.x * 256 + threadIdx.x) * 8;  // 524288 elems
  int k = (int)(i >> 11), e = (int)(i & 2047);
  size_t src = (size_t)k * NQKV_ + HD_ + e;
  short8 o;
  if (isbf) {
    const u16* q = (const u16*)qkv_w;
#pragma unroll
    for (int j = 0; j < 8; ++j) o[j] = (short)q[src + j];
  } else {
    const float* q = (const float*)qkv_w;
#pragma unroll
    for (int j = 0; j < 8; ++j) o[j] = (short)f2bf(q[src + j]);
  }
  *(short8*)&wv[i] = o;
}

// ---- pt[c][e] = bf16(proj_w[e][c]); 256 x 2048 ----
__global__ void tr_pt_kernel(const void* __restrict__ proj_w, u16* __restrict__ pt,
                             const int* __restrict__ flag) {
  int isbf = *flag;
  __shared__ float tile[32][33];
  int tx = threadIdx.x, ty = threadIdx.y;
  int c0 = blockIdx.x * 32, e0 = blockIdx.y * 32;
  for (int i = ty; i < 32; i += 8)
    tile[i][tx] = ldin(proj_w, (size_t)(e0 + i) * 256 + c0 + tx, isbf);
  __syncthreads();
  for (int i = ty; i < 32; i += 8)
    pt[(size_t)(c0 + i) * HD_ + e0 + tx] = f2bf(tile[tx][i]);
}

// ---- column sums of x ----
__global__ void colsum1_kernel(const void* __restrict__ x, float* __restrict__ part,
                               const int* __restrict__ flag) {
  int isbf = *flag;
  int b = blockIdx.x >> 4, chunk = blockIdx.x & 15, k = threadIdx.x;
  size_t base = ((size_t)b * N_ + (size_t)chunk * 256) * DIM_ + k;
  float s = 0.f;
  for (int n = 0; n < 256; ++n) s += ldin(x, base + (size_t)n * DIM_, isbf);
  part[(b * 16 + chunk) * DIM_ + k] = s;
}
__global__ void colsum2_kernel(const float* __restrict__ part, float* __restrict__ xsum) {
  int b = blockIdx.x, k = threadIdx.x;
  float s = 0.f;
  for (int c = 0; c < 16; ++c) s += part[(b * 16 + c) * DIM_ + k];
  xsum[b * DIM_ + k] = s;
}

// ---- Psum / bias cvt / lunchbox row-sum, one merged launch ----
__global__ void small_prep_kernel(const void* __restrict__ proj_w, const void* __restrict__ qkv_b,
                                  const void* __restrict__ proj_b, const void* __restrict__ lunchbox,
                                  float* __restrict__ Psum, float* __restrict__ qb,
                                  float* __restrict__ pbv, float* __restrict__ Lsum,
                                  const int* __restrict__ flag) {
  int isbf = *flag;
  int bid = blockIdx.x, t = threadIdx.x;
  if (bid < 256) {            // Psum[d][c] = sum_jj proj_w[jj*256+d][c]
    float s = 0.f;
    for (int jj = 0; jj < 8; ++jj) s += ldin(proj_w, (size_t)(jj * 256 + bid) * 256 + t, isbf);
    Psum[bid * 256 + t] = s;
  } else if (bid < 272) {     // qkv_b -> f32
    int i = (bid - 256) * 256 + t;
    qb[i] = ldin(qkv_b, i, isbf);
  } else if (bid == 272) {    // proj_b
    pbv[t] = ldin(proj_b, t, isbf);
  } else {                    // Lsum[d] = sum_r lunchbox[d][r]
    float s = 0.f;
    for (int r = 0; r < 32; ++r) s += ldin(lunchbox, (size_t)t * 32 + r, isbf);
    Lsum[t] = s;
  }
}

// ---- g[b][hd] and ub[b][hd] ----
__global__ void g_ub_kernel(const float* __restrict__ xsum, const void* __restrict__ qkv_w,
                            const float* __restrict__ qb, const float* __restrict__ Lsum,
                            float* __restrict__ g, float* __restrict__ ub,
                            const int* __restrict__ flag) {
  int isbf = *flag;
  int b = blockIdx.x >> 3, chunk = blockIdx.x & 7, t = threadIdx.x;
  __shared__ float xs[256];
  xs[t] = xsum[b * 256 + t];
  __syncthreads();
  int hd = chunk * 256 + t;
  float s = 0.f;
  for (int k = 0; k < 256; ++k) s += xs[k] * ldin(qkv_w, (size_t)k * NQKV_ + hd, isbf);
  float gg = 0.0625f * (s + 4096.0f * qb[hd]) * Lsum[hd & 255];
  g[b * HD_ + hd] = gg;
  ub[b * HD_ + hd] = gg * qb[HD_ + hd];
}

// ---- rcb[b*8+h][c] = sum_d ub[b][h*256+d]*Psum[d][c] + proj_b[c] ----
__global__ void rc_kernel(const float* __restrict__ ub, const float* __restrict__ Psum,
                          const float* __restrict__ pbv, float* __restrict__ rcb) {
  int bh = blockIdx.x, t = threadIdx.x;
  __shared__ float us[256];
  us[t] = ub[(bh >> 3) * HD_ + (bh & 7) * 256 + t];
  __syncthreads();
  float s = 0.f;
  for (int d = 0; d < 256; ++d) s += us[d] * Psum[d * 256 + t];
  rcb[bh * 256 + t] = s + pbv[t];
}

// ---- wg[b][k][e] = wv[k][e] * g[b][e]  (bf16, 8 elems/thread) ----
__global__ void wg_scale_kernel(const u16* __restrict__ wv, const float* __restrict__ g,
                                u16* __restrict__ wg) {
  int b = blockIdx.x >> 8;
  size_t i = ((size_t)(blockIdx.x & 255) * 256 + threadIdx.x) * 8;  // 524288 per b
  int e = (int)(i & 2047);
  short8 w8 = *(const short8*)&wv[i];
  f32x4 g0 = *(const f32x4*)&g[b * HD_ + e];
  f32x4 g1 = *(const f32x4*)&g[b * HD_ + e + 4];
  short8 o;
  o[0] = (short)f2bf(bf2f((u16)w8[0]) * g0[0]);
  o[1] = (short)f2bf(bf2f((u16)w8[1]) * g0[1]);
  o[2] = (short)f2bf(bf2f((u16)w8[2]) * g0[2]);
  o[3] = (short)f2bf(bf2f((u16)w8[3]) * g0[3]);
  o[4] = (short)f2bf(bf2f((u16)w8[4]) * g1[0]);
  o[5] = (short)f2bf(bf2f((u16)w8[5]) * g1[1]);
  o[6] = (short)f2bf(bf2f((u16)w8[6]) * g1[2]);
  o[7] = (short)f2bf(bf2f((u16)w8[7]) * g1[3]);
  *(short8*)&wg[(size_t)b * 524288 + i] = o;
}

// ---- stage 1: Mt[panel][c][jj*256+k] = sum_d pt[c][jj*256+d] * wg[b][k][h*256+d] ----
__global__ __launch_bounds__(256) void stage1_kernel(
    const u16* __restrict__ pt, const u16* __restrict__ wg,
    u16* __restrict__ Mt, int b0) {
  __shared__ alignas(16) char smemraw[16896];
  u16* lA = (u16*)smemraw;            // [128][32] pt tile (A: rows=c)
  u16* lB = (u16*)(smemraw + 8192);   // [128][32] wg tile (B^T: rows=k)
  float* eps = (float*)smemraw;       // 32 x 132 f32 epilogue

  int bid = blockIdx.x;
  int sub = bid & 3, jj = (bid >> 2) & 7, h = (bid >> 5) & 7, bb = bid >> 8;
  int b = b0 + bb;
  int c0 = (sub >> 1) * 128, k0 = (sub & 1) * 128;
  const u16* wgb = wg + (size_t)b * 524288;

  const int t = threadIdx.x, lane = t & 63, wave = t >> 6;
  const int wr = wave >> 1, wc = wave & 1;
  const int koff = (lane >> 4) * 8;

  f32x4 acc[4][4] = {};

  for (int ks = 0; ks < 8; ++ks) {
#pragma unroll
    for (int it = 0; it < 2; ++it) {
      int idx = it * 256 + t;
      int row = idx >> 2, kb = (idx & 3) * 8;
      load16_to_lds(pt + (size_t)(c0 + row) * HD_ + jj * 256 + ks * 32 + kb, lA + idx * 8);
    }
#pragma unroll
    for (int it = 0; it < 2; ++it) {
      int idx = it * 256 + t;
      int row = idx >> 2, kb = (idx & 3) * 8;
      load16_to_lds(wgb + (size_t)(k0 + row) * HD_ + h * 256 + ks * 32 + kb, lB + idx * 8);
    }
    __syncthreads();
    short8 af[4], bfr[4];
    const int ar = wr * 64 + (lane & 15), bc = wc * 64 + (lane & 15);
#pragma unroll
    for (int mi = 0; mi < 4; ++mi) af[mi] = *(const short8*)&lA[(ar + mi * 16) * 32 + koff];
#pragma unroll
    for (int ni = 0; ni < 4; ++ni) bfr[ni] = *(const short8*)&lB[(bc + ni * 16) * 32 + koff];
#pragma unroll
    for (int mi = 0; mi < 4; ++mi)
#pragma unroll
      for (int ni = 0; ni < 4; ++ni)
        acc[mi][ni] = __builtin_amdgcn_mfma_f32_16x16x32_bf16(af[mi], bfr[ni], acc[mi][ni], 0, 0, 0);
    __syncthreads();
  }

  // epilogue: Mt rows = c (row-major in k) -> coalesced
  const int panel = bb * 8 + h;
  const int rl = t >> 3, cc = (t & 7) * 16;
  u16* mrow_base = Mt + (size_t)panel * 524288;
#pragma unroll
  for (int mi = 0; mi < 4; ++mi) {
    __syncthreads();
#pragma unroll
    for (int ni = 0; ni < 4; ++ni) {
      f32x4 v = acc[mi][ni];
      int re = wr * 16 + (lane >> 4) * 4, ce = wc * 64 + ni * 16 + (lane & 15);
      eps[(re + 0) * 132 + ce] = v[0];
      eps[(re + 1) * 132 + ce] = v[1];
      eps[(re + 2) * 132 + ce] = v[2];
      eps[(re + 3) * 132 + ce] = v[3];
    }
    __syncthreads();
    int cg = c0 + (rl >> 4) * 64 + mi * 16 + (rl & 15);
    alignas(16) u16 pk[16];
#pragma unroll
    for (int j = 0; j < 16; ++j) pk[j] = f2bf(eps[rl * 132 + cc + j]);
    u16* dst = mrow_base + (size_t)cg * HD_ + jj * 256 + k0 + cc;
    *(short8*)dst = *(short8*)pk;
    *(short8*)(dst + 8) = *(short8*)(pk + 8);
  }
}

// ---- stage 2: out[b*4096+h*512+nn][c] = sum_e xb[b][nn][e] * Mt[panel][c][e] + rcb ----
__global__ __launch_bounds__(256) void stage2_kernel(
    const u16* __restrict__ xb, const u16* __restrict__ Mt,
    const float* __restrict__ rcb, void* __restrict__ outv,
    const int* __restrict__ flag, int b0, int nblk) {
  __shared__ alignas(16) char smemraw[16896];
  u16* lA = (u16*)smemraw;
  u16* lB = (u16*)(smemraw + 8192);
  float* eps = (float*)smemraw;

  // XCD-grouping swizzle (nblk divisible by 8)
  int bid = blockIdx.x;
  int sid = (bid & 7) * (nblk >> 3) + (bid >> 3);
  int ct = sid & 1, rt = (sid >> 1) & 3, h = (sid >> 3) & 7, bb = sid >> 6;
  int b = b0 + bb;
  int nn0 = rt * 128, c0 = ct * 128;
  const int panel = bb * 8 + h;
  const u16* Abase = xb + (size_t)b * 1048576 + (size_t)nn0 * HD_;
  const u16* Bbase = Mt + (size_t)panel * 524288 + (size_t)c0 * HD_;

  const int t = threadIdx.x, lane = t & 63, wave = t >> 6;
  const int wr = wave >> 1, wc = wave & 1;
  const int koff = (lane >> 4) * 8;

  f32x4 acc[4][4] = {};

  for (int ks = 0; ks < 64; ++ks) {
#pragma unroll
    for (int it = 0; it < 2; ++it) {
      int idx = it * 256 + t;
      int row = idx >> 2, kb = (idx & 3) * 8;
      load16_to_lds(Abase + (size_t)row * HD_ + ks * 32 + kb, lA + idx * 8);
    }
#pragma unroll
    for (int it = 0; it < 2; ++it) {
      int idx = it * 256 + t;
      int row = idx >> 2, kb = (idx & 3) * 8;
      load16_to_lds(Bbase + (size_t)row * HD_ + ks * 32 + kb, lB + idx * 8);
    }
    __syncthreads();
    short8 af[4], bfr[4];
    const int ar = wr * 64 + (lane & 15), bc = wc * 64 + (lane & 15);
#pragma unroll
    for (int mi = 0; mi < 4; ++mi) af[mi] = *(const short8*)&lA[(ar + mi * 16) * 32 + koff];
#pragma unroll
    for (int ni = 0; ni < 4; ++ni) bfr[ni] = *(const short8*)&lB[(bc + ni * 16) * 32 + koff];
#pragma unroll
    for (int mi = 0; mi < 4; ++mi)
#pragma unroll
      for (int ni = 0; ni < 4; ++ni)
        acc[mi][ni] = __builtin_amdgcn_mfma_f32_16x16x32_bf16(af[mi], bfr[ni], acc[mi][ni], 0, 0, 0);
    __syncthreads();
  }

  int isbf = *flag;
  const int rl = t >> 3, cc = (t & 7) * 16;
  const float* rcp = rcb + (size_t)(b * 8 + h) * 256 + c0 + cc;
  float rc[16];
#pragma unroll
  for (int j = 0; j < 16; ++j) rc[j] = rcp[j];
#pragma unroll
  for (int mi = 0; mi < 4; ++mi) {
    __syncthreads();
#pragma unroll
    for (int ni = 0; ni < 4; ++ni) {
      f32x4 v = acc[mi][ni];
      int re = wr * 16 + (lane >> 4) * 4, ce = wc * 64 + ni * 16 + (lane & 15);
      eps[(re + 0) * 132 + ce] = v[0];
      eps[(re + 1) * 132 + ce] = v[1];
      eps[(re + 2) * 132 + ce] = v[2];
      eps[(re + 3) * 132 + ce] = v[3];
    }
    __syncthreads();
    int grow = b * N_ + h * 512 + nn0 + (rl >> 4) * 64 + mi * 16 + (rl & 15);
    if (isbf) {
      alignas(16) u16 pk[16];
#pragma unroll
      for (int j = 0; j < 16; ++j) pk[j] = f2bf(eps[rl * 132 + cc + j] + rc[j]);
      u16* op = (u16*)outv + (size_t)grow * 256 + c0 + cc;
      *(short8*)op = *(short8*)pk;
      *(short8*)(op + 8) = *(short8*)(pk + 8);
    } else {
      float* op = (float*)outv + (size_t)grow * 256 + c0 + cc;
#pragma unroll
      for (int ch = 0; ch < 4; ++ch) {
        f32x4 o_;
        o_[0] = eps[rl * 132 + cc + ch * 4 + 0] + rc[ch * 4 + 0];
        o_[1] = eps[rl * 132 + cc + ch * 4 + 1] + rc[ch * 4 + 1];
        o_[2] = eps[rl * 132 + cc + ch * 4 + 2] + rc[ch * 4 + 2];
        o_[3] = eps[rl * 132 + cc + ch * 4 + 3] + rc[ch * 4 + 3];
        ((f32x4*)op)[ch] = o_;
      }
    }
  }
}

extern "C" void kernel_launch(void* const* d_in, const int* in_sizes, int n_in,
                              void* d_out, int out_size, void* d_ws, size_t ws_size,
                              hipStream_t stream) {
  const void* x        = d_in[0];
  const void* qkv_w    = d_in[1];
  const void* qkv_b    = d_in[2];
  const void* lunchbox = d_in[3];
  const void* proj_w   = d_in[4];
  const void* proj_b   = d_in[5];
  char* ws = (char*)d_ws;

  u16*   xbuf = (u16*)(ws + 0);            // 16 MiB
  u16*   wv   = (u16*)(ws + 16777216);     // 1 MiB
  u16*   pt   = (u16*)(ws + 17825792);     // 1 MiB
  float* part = (float*)(ws + 18874368);   // 128 KiB
  float* xsum = (float*)(ws + 19005440);   // 8 KiB
  float* g    = (float*)(ws + 19013632);   // 64 KiB
  float* ub   = (float*)(ws + 19079168);   // 64 KiB
  float* qb   = (float*)(ws + 19144704);   // 16 KiB
  float* pbv  = (float*)(ws + 19161088);   // 1 KiB
  float* Lsum = (float*)(ws + 19162112);   // 1 KiB
  float* Psum = (float*)(ws + 19163136);   // 256 KiB
  float* rcb  = (float*)(ws + 19425280);   // 64 KiB
  int*   flag = (int*)(ws + 19490816);     // 64 B
  u16*   wg   = (u16*)(ws + 19491840);     // 8 MiB
  u16*   Mt   = (u16*)(ws + 27880448);     // up to 64 MiB

  probe_kernel<<<1, 256, 0, stream>>>(x, flag);
  cvt_x_kernel<<<4096, 256, 0, stream>>>(x, xbuf, flag);
  cvt_wv_kernel<<<256, 256, 0, stream>>>(qkv_w, wv, flag);
  tr_pt_kernel<<<dim3(8, 64), dim3(32, 8), 0, stream>>>(proj_w, pt, flag);
  colsum1_kernel<<<128, 256, 0, stream>>>(x, part, flag);
  colsum2_kernel<<<8, 256, 0, stream>>>(part, xsum);
  small_prep_kernel<<<274, 256, 0, stream>>>(proj_w, qkv_b, proj_b, lunchbox,
                                             Psum, qb, pbv, Lsum, flag);
  g_ub_kernel<<<64, 256, 0, stream>>>(xsum, qkv_w, qb, Lsum, g, ub, flag);
  rc_kernel<<<64, 256, 0, stream>>>(ub, Psum, pbv, rcb);
  wg_scale_kernel<<<2048, 256, 0, stream>>>(wv, g, wg);

  // choose b-group size so Mt fits in remaining workspace
  size_t mt_off = 27880448;
  int gb = 8;
  while (gb > 1 && mt_off + (size_t)gb * 8 * 524288 * 2 > ws_size) gb >>= 1;
  for (int b0 = 0; b0 < 8; b0 += gb) {
    stage1_kernel<<<gb * 256, 256, 0, stream>>>(pt, wg, Mt, b0);
    int nblk = gb * 64;
    stage2_kernel<<<nblk, 256, 0, stream>>>(xbuf, Mt, rcb, d_out, flag, b0, nblk);
  }
}

// Round 4
// 161.258 us; speedup vs baseline: 1.3233x; 1.0969x over previous
//
#include <hip/hip_runtime.h>
#include <stdint.h>

typedef unsigned short u16;
typedef unsigned int u32;
typedef __attribute__((ext_vector_type(8))) short short8;
typedef __attribute__((ext_vector_type(4))) float f32x4;

#define B_    8
#define N_    4096
#define DIM_  256
#define HD_   2048
#define NQKV_ 4096

__device__ __forceinline__ float bf2f(u16 u) {
  union { u32 u; float f; } v; v.u = ((u32)u) << 16; return v.f;
}
__device__ __forceinline__ u16 f2bf(float f) {
  union { float f; u32 u; } v; v.f = f;
  u32 r = v.u + 0x7fffu + ((v.u >> 16) & 1u);
  return (u16)(r >> 16);
}
__device__ __forceinline__ float ldin(const void* p, size_t i, int isbf) {
  return isbf ? bf2f(((const u16*)p)[i]) : ((const float*)p)[i];
}
__device__ __forceinline__ void load16_to_lds(const u16* gsrc, u16* ldst) {
  auto gp = (const __attribute__((address_space(1))) void*)(uintptr_t)gsrc;
  auto lp = (__attribute__((address_space(3))) void*)(uintptr_t)ldst;
  __builtin_amdgcn_global_load_lds(gp, lp, 16, 0, 0);
}
// per-block dtype probe on x (nonzero input): bf16 -> low-u16 exponent plausible
__device__ __forceinline__ int probe_isbf(const void* x) {
  u32 w = ((const u32*)x)[threadIdx.x & 63];
  int e = (int)((w >> 7) & 0xff);
  unsigned long long m = __ballot(e >= 118 && e <= 130);
  return __popcll(m) >= 32;
}

// ---- x -> bf16 (8 elems/thread) ----
__global__ void cvt_x_kernel(const void* __restrict__ x, u16* __restrict__ xb) {
  int isbf = probe_isbf(x);
  size_t i = (size_t)blockIdx.x * 256 + threadIdx.x;  // 1048576 total
  if (isbf) {
    ((short8*)xb)[i] = ((const short8*)x)[i];
  } else {
    const f32x4* xp = (const f32x4*)x + i * 2;
    f32x4 a = xp[0], b = xp[1];
    short8 o;
    o[0] = (short)f2bf(a[0]); o[1] = (short)f2bf(a[1]);
    o[2] = (short)f2bf(a[2]); o[3] = (short)f2bf(a[3]);
    o[4] = (short)f2bf(b[0]); o[5] = (short)f2bf(b[1]);
    o[6] = (short)f2bf(b[2]); o[7] = (short)f2bf(b[3]);
    ((short8*)xb)[i] = o;
  }
}

// ---- fused prep: cvt_wv | tr_pt | colsum parts | Psum | qb | pbv | Lsum ----
__global__ void prep_kernel(const void* __restrict__ x, const void* __restrict__ qkv_w,
                            const void* __restrict__ proj_w, const void* __restrict__ qkv_b,
                            const void* __restrict__ proj_b, const void* __restrict__ lunchbox,
                            u16* __restrict__ wv, u16* __restrict__ pt,
                            float* __restrict__ part, float* __restrict__ Psum,
                            float* __restrict__ qb, float* __restrict__ pbv,
                            float* __restrict__ Lsum) {
  int isbf = probe_isbf(x);
  int bid = blockIdx.x, t = threadIdx.x;
  if (bid < 256) {
    // wv[k][e] = bf16(qkv_w[k][2048+e])
    size_t i = ((size_t)bid * 256 + t) * 8;
    int k = (int)(i >> 11), e = (int)(i & 2047);
    size_t src = (size_t)k * NQKV_ + HD_ + e;
    short8 o;
#pragma unroll
    for (int j = 0; j < 8; ++j) o[j] = (short)f2bf(ldin(qkv_w, src + j, isbf));
    *(short8*)&wv[i] = o;
  } else if (bid < 768) {
    // pt[c][e] = bf16(proj_w[e][c])
    __shared__ float tile[32][33];
    int bid2 = bid - 256;
    int c0 = (bid2 & 7) * 32, e0 = (bid2 >> 3) * 32;
    int tx = t & 31, ty = t >> 5;
    for (int i = ty; i < 32; i += 8)
      tile[i][tx] = ldin(proj_w, (size_t)(e0 + i) * 256 + c0 + tx, isbf);
    __syncthreads();
    for (int i = ty; i < 32; i += 8)
      pt[(size_t)(c0 + i) * HD_ + e0 + tx] = f2bf(tile[tx][i]);
  } else if (bid < 896) {
    // column-sum partials of x
    int bid2 = bid - 768;
    int b = bid2 >> 4, chunk = bid2 & 15;
    size_t base = ((size_t)b * N_ + (size_t)chunk * 256) * DIM_ + t;
    float s = 0.f;
    for (int n = 0; n < 256; ++n) s += ldin(x, base + (size_t)n * DIM_, isbf);
    part[(b * 16 + chunk) * DIM_ + t] = s;
  } else if (bid < 1152) {
    // Psum[d][c] = sum_jj proj_w[jj*256+d][c]
    int d = bid - 896;
    float s = 0.f;
    for (int jj = 0; jj < 8; ++jj) s += ldin(proj_w, (size_t)(jj * 256 + d) * 256 + t, isbf);
    Psum[d * 256 + t] = s;
  } else if (bid < 1168) {
    int i = (bid - 1152) * 256 + t;
    qb[i] = ldin(qkv_b, i, isbf);
  } else if (bid == 1168) {
    pbv[t] = ldin(proj_b, t, isbf);
  } else {
    float s = 0.f;
    for (int r = 0; r < 32; ++r) s += ldin(lunchbox, (size_t)t * 32 + r, isbf);
    Lsum[t] = s;
  }
}

// ---- fused colsum2 + g + ub + rc; one block per (b,h) ----
__global__ void gub_rc_kernel(const void* __restrict__ x, const void* __restrict__ qkv_w,
                              const float* __restrict__ part, const float* __restrict__ qb,
                              const float* __restrict__ pbv, const float* __restrict__ Lsum,
                              const float* __restrict__ Psum, float* __restrict__ g,
                              float* __restrict__ rcb) {
  int isbf = probe_isbf(x);
  int b = blockIdx.x >> 3, h = blockIdx.x & 7, t = threadIdx.x;
  __shared__ float xs[256];
  __shared__ float us[256];
  float s0 = 0.f;
  for (int c = 0; c < 16; ++c) s0 += part[(b * 16 + c) * DIM_ + t];
  xs[t] = s0;
  __syncthreads();
  int hd = h * 256 + t;
  float s = 0.f;
  for (int k = 0; k < 256; ++k) s += xs[k] * ldin(qkv_w, (size_t)k * NQKV_ + hd, isbf);
  float gg = 0.0625f * (s + 4096.0f * qb[hd]) * Lsum[t];
  g[b * HD_ + hd] = gg;
  us[t] = gg * qb[HD_ + hd];
  __syncthreads();
  float r = 0.f;
  for (int d = 0; d < 256; ++d) r += us[d] * Psum[d * 256 + t];
  rcb[blockIdx.x * 256 + t] = r + pbv[t];
}

// ---- stage 1 (dbuf + fused g-scale): Mt[panel][c][jj*256+k] = sum_d pt[c][jj*256+d]*wv[k][h*256+d]*g[b][h*256+d] ----
__global__ __launch_bounds__(256) void stage1_kernel(
    const u16* __restrict__ pt, const u16* __restrict__ wv,
    const float* __restrict__ g, u16* __restrict__ Mt, int b0) {
  __shared__ alignas(16) char smemraw[33792];  // [0,16K)=buf0 [16K,32K)=buf1 [32K,+1K)=gsh
  float* gsh = (float*)(smemraw + 32768);
  float* eps = (float*)smemraw;

  int bid = blockIdx.x;
  int sub = bid & 3, jj = (bid >> 2) & 7, h = (bid >> 5) & 7, bb = bid >> 8;
  int b = b0 + bb;
  int c0 = (sub >> 1) * 128, k0 = (sub & 1) * 128;
  const int t = threadIdx.x, lane = t & 63, wave = t >> 6;
  const int wr = wave >> 1, wc = wave & 1;
  const int koff = (lane >> 4) * 8;

  gsh[t] = g[b * HD_ + h * 256 + t];

  f32x4 acc[4][4] = {};
  short8 breg0, breg1;

#define S1_STAGE_A(ks, bi)                                                              \
  {                                                                                     \
    _Pragma("unroll") for (int it = 0; it < 2; ++it) {                                  \
      int idx = it * 256 + t, row = idx >> 2, kb = (idx & 3) * 8;                       \
      load16_to_lds(pt + (size_t)(c0 + row) * HD_ + jj * 256 + (ks) * 32 + kb,         \
                    (u16*)(smemraw + (bi) * 16384) + idx * 8);                          \
    }                                                                                   \
  }
#define S1_LOAD_B(ks)                                                                   \
  {                                                                                     \
    int idx0 = t, row0 = idx0 >> 2, kb0 = (idx0 & 3) * 8;                               \
    breg0 = *(const short8*)&wv[(size_t)(k0 + row0) * HD_ + h * 256 + (ks) * 32 + kb0]; \
    int idx1 = 256 + t, row1 = idx1 >> 2, kb1 = (idx1 & 3) * 8;                         \
    breg1 = *(const short8*)&wv[(size_t)(k0 + row1) * HD_ + h * 256 + (ks) * 32 + kb1]; \
  }
#define S1_WRITE_B(ks, bi)                                                              \
  {                                                                                     \
    _Pragma("unroll") for (int it = 0; it < 2; ++it) {                                  \
      int idx = it * 256 + t, kb = (idx & 3) * 8, d0 = (ks) * 32 + kb;                  \
      short8 w8 = it ? breg1 : breg0;                                                   \
      short8 o;                                                                         \
      _Pragma("unroll") for (int j = 0; j < 8; ++j)                                     \
          o[j] = (short)f2bf(bf2f((u16)w8[j]) * gsh[d0 + j]);                           \
      *(short8*)((u16*)(smemraw + (bi) * 16384 + 8192) + idx * 8) = o;                  \
    }                                                                                   \
  }

  // prologue
  S1_LOAD_B(0);
  S1_STAGE_A(0, 0);
  __syncthreads();     // gsh visible to all
  S1_WRITE_B(0, 0);
  __syncthreads();     // drains vmcnt (A staged) + lgkm (B written)

  int cur = 0;
  for (int ks = 0; ks < 8; ++ks) {
    if (ks < 7) {
      S1_STAGE_A(ks + 1, cur ^ 1);
      S1_LOAD_B(ks + 1);
    }
    const u16* lA = (const u16*)(smemraw + cur * 16384);
    const u16* lB = lA + 4096;
    short8 af[4], bfr[4];
    const int ar = wr * 64 + (lane & 15), bc = wc * 64 + (lane & 15);
#pragma unroll
    for (int mi = 0; mi < 4; ++mi) af[mi] = *(const short8*)&lA[(ar + mi * 16) * 32 + koff];
#pragma unroll
    for (int ni = 0; ni < 4; ++ni) bfr[ni] = *(const short8*)&lB[(bc + ni * 16) * 32 + koff];
#pragma unroll
    for (int mi = 0; mi < 4; ++mi)
#pragma unroll
      for (int ni = 0; ni < 4; ++ni)
        acc[mi][ni] = __builtin_amdgcn_mfma_f32_16x16x32_bf16(af[mi], bfr[ni], acc[mi][ni], 0, 0, 0);
    if (ks < 7) S1_WRITE_B(ks + 1, cur ^ 1);
    __syncthreads();
    cur ^= 1;
  }

  // epilogue: Mt rows = c, row-major in k' = jj*256+k
  const int panel = bb * 8 + h;
  const int rl = t >> 3, cc = (t & 7) * 16;
  u16* mrow_base = Mt + (size_t)panel * 524288;
#pragma unroll
  for (int mi = 0; mi < 4; ++mi) {
    __syncthreads();
#pragma unroll
    for (int ni = 0; ni < 4; ++ni) {
      f32x4 v = acc[mi][ni];
      int re = wr * 16 + (lane >> 4) * 4, ce = wc * 64 + ni * 16 + (lane & 15);
      eps[(re + 0) * 132 + ce] = v[0];
      eps[(re + 1) * 132 + ce] = v[1];
      eps[(re + 2) * 132 + ce] = v[2];
      eps[(re + 3) * 132 + ce] = v[3];
    }
    __syncthreads();
    int cg = c0 + (rl >> 4) * 64 + mi * 16 + (rl & 15);
    alignas(16) u16 pk[16];
#pragma unroll
    for (int j = 0; j < 16; ++j) pk[j] = f2bf(eps[rl * 132 + cc + j]);
    u16* dst = mrow_base + (size_t)cg * HD_ + jj * 256 + k0 + cc;
    *(short8*)dst = *(short8*)pk;
    *(short8*)(dst + 8) = *(short8*)(pk + 8);
  }
}

// ---- stage 2 (dbuf): out[b*4096+h*512+nn][c] = sum_e xb_resh[b][nn][e]*Mt[panel][c][e] + rcb ----
__global__ __launch_bounds__(256) void stage2_kernel(
    const void* __restrict__ xraw, const u16* __restrict__ xb, const u16* __restrict__ Mt,
    const float* __restrict__ rcb, void* __restrict__ outv, int b0, int nblk) {
  __shared__ alignas(16) char smemraw[32768];  // two 16KB (A+B) buffers
  float* eps = (float*)smemraw;

  int bid = blockIdx.x;
  int sid = (bid & 7) * (nblk >> 3) + (bid >> 3);   // XCD-contiguous
  int ct = sid & 1, rt = (sid >> 1) & 3, h = (sid >> 3) & 7, bb = sid >> 6;
  int b = b0 + bb;
  int nn0 = rt * 128, c0 = ct * 128;
  const int panel = bb * 8 + h;
  const u16* Abase = xb + (size_t)b * 1048576 + (size_t)nn0 * HD_;
  const u16* Bbase = Mt + (size_t)panel * 524288 + (size_t)c0 * HD_;

  const int t = threadIdx.x, lane = t & 63, wave = t >> 6;
  const int wr = wave >> 1, wc = wave & 1;
  const int koff = (lane >> 4) * 8;

  f32x4 acc[4][4] = {};

#define S2_STAGE(ks, bi)                                                            \
  {                                                                                 \
    _Pragma("unroll") for (int it = 0; it < 2; ++it) {                              \
      int idx = it * 256 + t, row = idx >> 2, kb = (idx & 3) * 8;                   \
      load16_to_lds(Abase + (size_t)row * HD_ + (ks) * 32 + kb,                     \
                    (u16*)(smemraw + (bi) * 16384) + idx * 8);                      \
      load16_to_lds(Bbase + (size_t)row * HD_ + (ks) * 32 + kb,                     \
                    (u16*)(smemraw + (bi) * 16384 + 8192) + idx * 8);               \
    }                                                                               \
  }

  S2_STAGE(0, 0);
  __syncthreads();

  int cur = 0;
  for (int ks = 0; ks < 64; ++ks) {
    if (ks < 63) S2_STAGE(ks + 1, cur ^ 1);
    const u16* lA = (const u16*)(smemraw + cur * 16384);
    const u16* lB = lA + 4096;
    short8 af[4], bfr[4];
    const int ar = wr * 64 + (lane & 15), bc = wc * 64 + (lane & 15);
#pragma unroll
    for (int mi = 0; mi < 4; ++mi) af[mi] = *(const short8*)&lA[(ar + mi * 16) * 32 + koff];
#pragma unroll
    for (int ni = 0; ni < 4; ++ni) bfr[ni] = *(const short8*)&lB[(bc + ni * 16) * 32 + koff];
#pragma unroll
    for (int mi = 0; mi < 4; ++mi)
#pragma unroll
      for (int ni = 0; ni < 4; ++ni)
        acc[mi][ni] = __builtin_amdgcn_mfma_f32_16x16x32_bf16(af[mi], bfr[ni], acc[mi][ni], 0, 0, 0);
    __syncthreads();
    cur ^= 1;
  }

  int isbf = probe_isbf(xraw);
  const int rl = t >> 3, cc = (t & 7) * 16;
  const float* rcp = rcb + (size_t)(b * 8 + h) * 256 + c0 + cc;
  float rc[16];
#pragma unroll
  for (int j = 0; j < 16; ++j) rc[j] = rcp[j];
#pragma unroll
  for (int mi = 0; mi < 4; ++mi) {
    __syncthreads();
#pragma unroll
    for (int ni = 0; ni < 4; ++ni) {
      f32x4 v = acc[mi][ni];
      int re = wr * 16 + (lane >> 4) * 4, ce = wc * 64 + ni * 16 + (lane & 15);
      eps[(re + 0) * 132 + ce] = v[0];
      eps[(re + 1) * 132 + ce] = v[1];
      eps[(re + 2) * 132 + ce] = v[2];
      eps[(re + 3) * 132 + ce] = v[3];
    }
    __syncthreads();
    int grow = b * N_ + h * 512 + nn0 + (rl >> 4) * 64 + mi * 16 + (rl & 15);
    if (isbf) {
      alignas(16) u16 pk[16];
#pragma unroll
      for (int j = 0; j < 16; ++j) pk[j] = f2bf(eps[rl * 132 + cc + j] + rc[j]);
      u16* op = (u16*)outv + (size_t)grow * 256 + c0 + cc;
      *(short8*)op = *(short8*)pk;
      *(short8*)(op + 8) = *(short8*)(pk + 8);
    } else {
      float* op = (float*)outv + (size_t)grow * 256 + c0 + cc;
#pragma unroll
      for (int ch = 0; ch < 4; ++ch) {
        f32x4 o_;
        o_[0] = eps[rl * 132 + cc + ch * 4 + 0] + rc[ch * 4 + 0];
        o_[1] = eps[rl * 132 + cc + ch * 4 + 1] + rc[ch * 4 + 1];
        o_[2] = eps[rl * 132 + cc + ch * 4 + 2] + rc[ch * 4 + 2];
        o_[3] = eps[rl * 132 + cc + ch * 4 + 3] + rc[ch * 4 + 3];
        ((f32x4*)op)[ch] = o_;
      }
    }
  }
}

extern "C" void kernel_launch(void* const* d_in, const int* in_sizes, int n_in,
                              void* d_out, int out_size, void* d_ws, size_t ws_size,
                              hipStream_t stream) {
  const void* x        = d_in[0];
  const void* qkv_w    = d_in[1];
  const void* qkv_b    = d_in[2];
  const void* lunchbox = d_in[3];
  const void* proj_w   = d_in[4];
  const void* proj_b   = d_in[5];
  char* ws = (char*)d_ws;

  u16*   xbuf = (u16*)(ws + 0);            // 16 MiB
  u16*   wv   = (u16*)(ws + 16777216);     // 1 MiB
  u16*   pt   = (u16*)(ws + 17825792);     // 1 MiB
  float* part = (float*)(ws + 18874368);   // 128 KiB
  float* g    = (float*)(ws + 19013632);   // 64 KiB
  float* qb   = (float*)(ws + 19079168);   // 16 KiB
  float* pbv  = (float*)(ws + 19095552);   // 1 KiB
  float* Lsum = (float*)(ws + 19096576);   // 1 KiB
  float* Psum = (float*)(ws + 19097600);   // 256 KiB
  float* rcb  = (float*)(ws + 19359744);   // 64 KiB
  u16*   Mt   = (u16*)(ws + 19425280);     // up to 64 MiB

  cvt_x_kernel<<<4096, 256, 0, stream>>>(x, xbuf);
  prep_kernel<<<1170, 256, 0, stream>>>(x, qkv_w, proj_w, qkv_b, proj_b, lunchbox,
                                        wv, pt, part, Psum, qb, pbv, Lsum);
  gub_rc_kernel<<<64, 256, 0, stream>>>(x, qkv_w, part, qb, pbv, Lsum, Psum, g, rcb);

  // b-group so Mt fits in workspace
  size_t mt_off = 19425280;
  int gb = 8;
  while (gb > 1 && mt_off + (size_t)gb * 8388608 > ws_size) gb >>= 1;
  for (int b0 = 0; b0 < 8; b0 += gb) {
    stage1_kernel<<<gb * 256, 256, 0, stream>>>(pt, wv, g, Mt, b0);
    int nblk = gb * 64;
    stage2_kernel<<<nblk, 256, 0, stream>>>(x, xbuf, Mt, rcb, d_out, b0, nblk);
  }
}

// Round 6
// 128.359 us; speedup vs baseline: 1.6624x; 1.2563x over previous
//
#include <hip/hip_runtime.h>
#include <stdint.h>

typedef unsigned short u16;
typedef unsigned int u32;
typedef __attribute__((ext_vector_type(8))) short short8;
typedef __attribute__((ext_vector_type(4))) float f32x4;

#define B_    8
#define N_    4096
#define DIM_  256
#define HD_   2048
#define NQKV_ 4096

__device__ __forceinline__ float bf2f(u16 u) {
  union { u32 u; float f; } v; v.u = ((u32)u) << 16; return v.f;
}
__device__ __forceinline__ u16 f2bf(float f) {
  union { float f; u32 u; } v; v.f = f;
  u32 r = v.u + 0x7fffu + ((v.u >> 16) & 1u);
  return (u16)(r >> 16);
}
__device__ __forceinline__ float ldin(const void* p, size_t i, int isbf) {
  return isbf ? bf2f(((const u16*)p)[i]) : ((const float*)p)[i];
}
__device__ __forceinline__ void load16_to_lds(const u16* gsrc, u16* ldst) {
  auto gp = (const __attribute__((address_space(1))) void*)(uintptr_t)gsrc;
  auto lp = (__attribute__((address_space(3))) void*)(uintptr_t)ldst;
  __builtin_amdgcn_global_load_lds(gp, lp, 16, 0, 0);
}
__device__ __forceinline__ int probe_isbf(const void* x) {
  u32 w = ((const u32*)x)[threadIdx.x & 63];
  int e = (int)((w >> 7) & 0xff);
  unsigned long long m = __ballot(e >= 118 && e <= 130);
  return __popcll(m) >= 32;
}

// ---- x -> bf16 + column-sum partials (x read ONCE) ----
__global__ void cvtsum_kernel(const void* __restrict__ x, u16* __restrict__ xb,
                              float* __restrict__ part) {
  int isbf = probe_isbf(x);
  int b = blockIdx.x >> 7, ch = blockIdx.x & 127, t = threadIdx.x;
  size_t base = ((size_t)b * N_ + (size_t)ch * 32) * DIM_ + t;
  float s = 0.f;
  for (int n = 0; n < 32; ++n) {
    float v = ldin(x, base + (size_t)n * DIM_, isbf);
    xb[base + (size_t)n * DIM_] = f2bf(v);
    s += v;
  }
  part[(b * 128 + ch) * DIM_ + t] = s;
}

// ---- fused prep: cvt_wv | tr_pt | Psum | qb | pbv | Lsum ----
__global__ void prep_kernel(const void* __restrict__ x, const void* __restrict__ qkv_w,
                            const void* __restrict__ proj_w, const void* __restrict__ qkv_b,
                            const void* __restrict__ proj_b, const void* __restrict__ lunchbox,
                            u16* __restrict__ wv, u16* __restrict__ pt,
                            float* __restrict__ Psum, float* __restrict__ qb,
                            float* __restrict__ pbv, float* __restrict__ Lsum) {
  int isbf = probe_isbf(x);
  int bid = blockIdx.x, t = threadIdx.x;
  if (bid < 256) {
    size_t i = ((size_t)bid * 256 + t) * 8;
    int k = (int)(i >> 11), e = (int)(i & 2047);
    size_t src = (size_t)k * NQKV_ + HD_ + e;
    short8 o;
#pragma unroll
    for (int j = 0; j < 8; ++j) o[j] = (short)f2bf(ldin(qkv_w, src + j, isbf));
    *(short8*)&wv[i] = o;
  } else if (bid < 768) {
    __shared__ float tile[32][33];
    int bid2 = bid - 256;
    int c0 = (bid2 & 7) * 32, e0 = (bid2 >> 3) * 32;
    int tx = t & 31, ty = t >> 5;
    for (int i = ty; i < 32; i += 8)
      tile[i][tx] = ldin(proj_w, (size_t)(e0 + i) * 256 + c0 + tx, isbf);
    __syncthreads();
    for (int i = ty; i < 32; i += 8)
      pt[(size_t)(c0 + i) * HD_ + e0 + tx] = f2bf(tile[tx][i]);
  } else if (bid < 1024) {
    int d = bid - 768;
    float s = 0.f;
    for (int jj = 0; jj < 8; ++jj) s += ldin(proj_w, (size_t)(jj * 256 + d) * 256 + t, isbf);
    Psum[d * 256 + t] = s;
  } else if (bid < 1040) {
    int i = (bid - 1024) * 256 + t;
    qb[i] = ldin(qkv_b, i, isbf);
  } else if (bid == 1040) {
    pbv[t] = ldin(proj_b, t, isbf);
  } else {
    float s = 0.f;
    for (int r = 0; r < 32; ++r) s += ldin(lunchbox, (size_t)t * 32 + r, isbf);
    Lsum[t] = s;
  }
}

// ---- fused colsum-final + g + rc; one block per (b,h) ----
__global__ void gub_rc_kernel(const void* __restrict__ x, const void* __restrict__ qkv_w,
                              const float* __restrict__ part, const float* __restrict__ qb,
                              const float* __restrict__ pbv, const float* __restrict__ Lsum,
                              const float* __restrict__ Psum, float* __restrict__ g,
                              float* __restrict__ rcb) {
  int isbf = probe_isbf(x);
  int b = blockIdx.x >> 3, h = blockIdx.x & 7, t = threadIdx.x;
  __shared__ float xs[256];
  __shared__ float us[256];
  float s0 = 0.f;
  for (int c = 0; c < 128; ++c) s0 += part[(b * 128 + c) * DIM_ + t];
  xs[t] = s0;
  __syncthreads();
  int hd = h * 256 + t;
  float s = 0.f;
  for (int k = 0; k < 256; ++k) s += xs[k] * ldin(qkv_w, (size_t)k * NQKV_ + hd, isbf);
  float gg = 0.0625f * (s + 4096.0f * qb[hd]) * Lsum[t];
  g[b * HD_ + hd] = gg;
  us[t] = gg * qb[HD_ + hd];
  __syncthreads();
  float r = 0.f;
  for (int d = 0; d < 256; ++d) r += us[d] * Psum[d * 256 + t];
  rcb[blockIdx.x * 256 + t] = r + pbv[t];
}

// ---- stage 1 v2: W'(g-scaled, swizzled) in LDS, reused across 4 jj-tiles ----
// Mt[panel][c][jj*256+k] = sum_d pt[c][jj*256+d] * wv[k][h*256+d] * g[b][h*256+d]
__global__ __launch_bounds__(256, 2) void stage1_kernel(
    const u16* __restrict__ pt, const u16* __restrict__ wv,
    const float* __restrict__ g, u16* __restrict__ Mt, int b0) {
  __shared__ alignas(16) char smem[81920];  // [0,64K)=W'  [64K,80K)=A dbuf / eps alias
  u16* Wp = (u16*)smem;
  char* Adb = smem + 65536;
  float* eps = (float*)(smem + 65536);

  int bid = blockIdx.x;
  int c0i = bid & 1, jh = (bid >> 1) & 1, k0i = (bid >> 2) & 1;
  int h = (bid >> 3) & 7, bb = bid >> 6;
  int b = b0 + bb;
  int c0 = c0i * 128, k0 = k0i * 128;
  const int t = threadIdx.x, lane = t & 63, wave = t >> 6;
  const int wr = wave >> 1, wc = wave & 1;
  const int panel = bb * 8 + h;

  // build W'[128 k][256 d], bf16, swizzled
  {
    const u16* wsrc = wv + (size_t)k0 * HD_ + h * 256;
    const float* gp = g + b * HD_ + h * 256;
#pragma unroll
    for (int it = 0; it < 16; ++it) {
      int idx = it * 256 + t;
      int row = idx >> 5, chunk = idx & 31;
      short8 w8 = *(const short8*)&wsrc[(size_t)row * HD_ + chunk * 8];
      f32x4 g0 = *(const f32x4*)&gp[chunk * 8];
      f32x4 g1 = *(const f32x4*)&gp[chunk * 8 + 4];
      short8 o;
      o[0] = (short)f2bf(bf2f((u16)w8[0]) * g0[0]);
      o[1] = (short)f2bf(bf2f((u16)w8[1]) * g0[1]);
      o[2] = (short)f2bf(bf2f((u16)w8[2]) * g0[2]);
      o[3] = (short)f2bf(bf2f((u16)w8[3]) * g0[3]);
      o[4] = (short)f2bf(bf2f((u16)w8[4]) * g1[0]);
      o[5] = (short)f2bf(bf2f((u16)w8[5]) * g1[1]);
      o[6] = (short)f2bf(bf2f((u16)w8[6]) * g1[2]);
      o[7] = (short)f2bf(bf2f((u16)w8[7]) * g1[3]);
      *(short8*)&Wp[row * 256 + ((chunk ^ (row & 7)) * 8)] = o;
    }
  }
  __syncthreads();

#define S1_STAGE(jj, ks, bi)                                                          \
  {                                                                                   \
    _Pragma("unroll") for (int it = 0; it < 2; ++it) {                                \
      int idx = it * 256 + t, row = idx >> 2, slot = idx & 3;                         \
      load16_to_lds(pt + (size_t)(c0 + row) * HD_ + (jj) * 256 + (ks) * 32 +          \
                        ((slot ^ (row & 3)) * 8),                                     \
                    (u16*)(Adb + (bi) * 8192) + idx * 8);                             \
    }                                                                                 \
  }

  for (int jc = 0; jc < 4; ++jc) {
    int jj = jh * 4 + jc;
    f32x4 acc[4][4] = {};
    S1_STAGE(jj, 0, 0);
    __syncthreads();
    int cur = 0;
    for (int ks = 0; ks < 8; ++ks) {
      if (ks < 7) S1_STAGE(jj, ks + 1, cur ^ 1);
      const u16* lA = (const u16*)(Adb + cur * 8192);
      short8 af[4], bfr[4];
      const int ar = wr * 64 + (lane & 15), bc = wc * 64 + (lane & 15);
#pragma unroll
      for (int mi = 0; mi < 4; ++mi) {
        int row = ar + mi * 16;
        af[mi] = *(const short8*)&lA[row * 32 + (((lane >> 4) ^ (row & 3)) * 8)];
      }
#pragma unroll
      for (int ni = 0; ni < 4; ++ni) {
        int kl = bc + ni * 16;
        int chunk = ks * 4 + (lane >> 4);
        bfr[ni] = *(const short8*)&Wp[kl * 256 + ((chunk ^ (kl & 7)) * 8)];
      }
#pragma unroll
      for (int mi = 0; mi < 4; ++mi)
#pragma unroll
        for (int ni = 0; ni < 4; ++ni)
          acc[mi][ni] = __builtin_amdgcn_mfma_f32_16x16x32_bf16(af[mi], bfr[ni], acc[mi][ni], 0, 0, 0);
      __syncthreads();
      cur ^= 1;
    }
    // epilogue: tile (c0..+128) x (jj*256 + k0..+128)
    const int rl = t >> 3, cc = (t & 7) * 16;
#pragma unroll
    for (int mi = 0; mi < 4; ++mi) {
      __syncthreads();
#pragma unroll
      for (int ni = 0; ni < 4; ++ni) {
        f32x4 v = acc[mi][ni];
        int re = wr * 16 + (lane >> 4) * 4, ce = wc * 64 + ni * 16 + (lane & 15);
        eps[(re + 0) * 128 + ce] = v[0];
        eps[(re + 1) * 128 + ce] = v[1];
        eps[(re + 2) * 128 + ce] = v[2];
        eps[(re + 3) * 128 + ce] = v[3];
      }
      __syncthreads();
      int cg = c0 + (rl >> 4) * 64 + mi * 16 + (rl & 15);
      alignas(16) u16 pk[16];
#pragma unroll
      for (int j = 0; j < 16; ++j) pk[j] = f2bf(eps[rl * 128 + cc + j]);
      u16* dst = Mt + (size_t)panel * 524288 + (size_t)cg * HD_ + jj * 256 + k0 + cc;
      *(short8*)dst = *(short8*)pk;
      *(short8*)(dst + 8) = *(short8*)(pk + 8);
    }
    __syncthreads();  // eps reads done before next jc restages Adb
  }
}

// ---- stage 2 v2: in-block split-K, 512 thr, 2 k-groups, swizzled tiles ----
__global__ __launch_bounds__(512, 4) void stage2_kernel(
    const void* __restrict__ xraw, const u16* __restrict__ xb, const u16* __restrict__ Mt,
    const float* __restrict__ rcb, void* __restrict__ outv, int b0, int nblk) {
  __shared__ alignas(16) char smem[65536];  // grp0: [0,32K) dbuf; grp1: [32K,64K); eps aliases [0,16K)
  float* eps = (float*)smem;

  int bid = blockIdx.x;
  int sid = (bid & 7) * (nblk >> 3) + (bid >> 3);  // XCD-contiguous
  int ct = sid & 1, rt = (sid >> 1) & 3, h = (sid >> 3) & 7, bb = sid >> 6;
  int b = b0 + bb;
  int nn0 = rt * 128, c0 = ct * 128;
  const int panel = bb * 8 + h;
  const u16* Abase = xb + (size_t)b * 1048576 + (size_t)nn0 * HD_;
  const u16* Bbase = Mt + (size_t)panel * 524288 + (size_t)c0 * HD_;

  const int t = threadIdx.x;
  const int grp = t >> 8, tt = t & 255;
  const int lane = tt & 63, wave = tt >> 6;
  const int wr = wave >> 1, wc = wave & 1;
  char* mybuf = smem + grp * 32768;

  f32x4 acc[4][4] = {};

#define S2_STAGE(i, bi)                                                            \
  {                                                                                \
    int kcol = ((i) * 2 + grp) * 32;                                               \
    _Pragma("unroll") for (int it = 0; it < 2; ++it) {                             \
      int idx = it * 256 + tt, row = idx >> 2, slot = idx & 3;                     \
      int sc = kcol + ((slot ^ (row & 3)) * 8);                                    \
      load16_to_lds(Abase + (size_t)row * HD_ + sc,                                \
                    (u16*)(mybuf + (bi) * 16384) + idx * 8);                       \
      load16_to_lds(Bbase + (size_t)row * HD_ + sc,                                \
                    (u16*)(mybuf + (bi) * 16384 + 8192) + idx * 8);                \
    }                                                                              \
  }

  S2_STAGE(0, 0);
  __syncthreads();
  int cur = 0;
  for (int i = 0; i < 32; ++i) {
    if (i < 31) S2_STAGE(i + 1, cur ^ 1);
    const u16* lA = (const u16*)(mybuf + cur * 16384);
    const u16* lB = lA + 4096;
    short8 af[4], bfr[4];
    const int ar = wr * 64 + (lane & 15), bc = wc * 64 + (lane & 15);
#pragma unroll
    for (int mi = 0; mi < 4; ++mi) {
      int row = ar + mi * 16;
      af[mi] = *(const short8*)&lA[row * 32 + (((lane >> 4) ^ (row & 3)) * 8)];
    }
#pragma unroll
    for (int ni = 0; ni < 4; ++ni) {
      int row = bc + ni * 16;
      bfr[ni] = *(const short8*)&lB[row * 32 + (((lane >> 4) ^ (row & 3)) * 8)];
    }
#pragma unroll
    for (int mi = 0; mi < 4; ++mi)
#pragma unroll
      for (int ni = 0; ni < 4; ++ni)
        acc[mi][ni] = __builtin_amdgcn_mfma_f32_16x16x32_bf16(af[mi], bfr[ni], acc[mi][ni], 0, 0, 0);
    __syncthreads();
    cur ^= 1;
  }

  // merge epilogue: eps = grp0 + grp1, then store
  int isbf = probe_isbf(xraw);
  const int rl = t >> 4, cc = (t & 15) * 8;
  float rc[8];
  const float* rcp = rcb + (size_t)(b * 8 + h) * 256 + c0 + cc;
#pragma unroll
  for (int j = 0; j < 8; ++j) rc[j] = rcp[j];
#pragma unroll
  for (int mi = 0; mi < 4; ++mi) {
    __syncthreads();
    if (grp == 0) {
#pragma unroll
      for (int ni = 0; ni < 4; ++ni) {
        f32x4 v = acc[mi][ni];
        int re = wr * 16 + (lane >> 4) * 4, ce = wc * 64 + ni * 16 + (lane & 15);
        eps[(re + 0) * 128 + ce] = v[0];
        eps[(re + 1) * 128 + ce] = v[1];
        eps[(re + 2) * 128 + ce] = v[2];
        eps[(re + 3) * 128 + ce] = v[3];
      }
    }
    __syncthreads();
    if (grp == 1) {
#pragma unroll
      for (int ni = 0; ni < 4; ++ni) {
        f32x4 v = acc[mi][ni];
        int re = wr * 16 + (lane >> 4) * 4, ce = wc * 64 + ni * 16 + (lane & 15);
        eps[(re + 0) * 128 + ce] += v[0];
        eps[(re + 1) * 128 + ce] += v[1];
        eps[(re + 2) * 128 + ce] += v[2];
        eps[(re + 3) * 128 + ce] += v[3];
      }
    }
    __syncthreads();
    int grow = b * N_ + h * 512 + nn0 + (rl >> 4) * 64 + mi * 16 + (rl & 15);
    if (isbf) {
      alignas(16) u16 pk[8];
#pragma unroll
      for (int j = 0; j < 8; ++j) pk[j] = f2bf(eps[rl * 128 + cc + j] + rc[j]);
      *(short8*)((u16*)outv + (size_t)grow * 256 + c0 + cc) = *(short8*)pk;
    } else {
      float* op = (float*)outv + (size_t)grow * 256 + c0 + cc;
      f32x4 o0, o1;
      o0[0] = eps[rl * 128 + cc + 0] + rc[0];
      o0[1] = eps[rl * 128 + cc + 1] + rc[1];
      o0[2] = eps[rl * 128 + cc + 2] + rc[2];
      o0[3] = eps[rl * 128 + cc + 3] + rc[3];
      o1[0] = eps[rl * 128 + cc + 4] + rc[4];
      o1[1] = eps[rl * 128 + cc + 5] + rc[5];
      o1[2] = eps[rl * 128 + cc + 6] + rc[6];
      o1[3] = eps[rl * 128 + cc + 7] + rc[7];
      ((f32x4*)op)[0] = o0;
      ((f32x4*)op)[1] = o1;
    }
  }
}

extern "C" void kernel_launch(void* const* d_in, const int* in_sizes, int n_in,
                              void* d_out, int out_size, void* d_ws, size_t ws_size,
                              hipStream_t stream) {
  const void* x        = d_in[0];
  const void* qkv_w    = d_in[1];
  const void* qkv_b    = d_in[2];
  const void* lunchbox = d_in[3];
  const void* proj_w   = d_in[4];
  const void* proj_b   = d_in[5];
  char* ws = (char*)d_ws;

  // workspace layout — FIXED: part now has a full 1 MiB (8*128*256 f32)
  u16*   xbuf = (u16*)(ws + 0);            // 16 MiB   [0, 16777216)
  u16*   wv   = (u16*)(ws + 16777216);     // 1 MiB    [16777216, 17825792)
  u16*   pt   = (u16*)(ws + 17825792);     // 1 MiB    [17825792, 18874368)
  float* part = (float*)(ws + 18874368);   // 1 MiB    [18874368, 19922944)
  float* g    = (float*)(ws + 19922944);   // 64 KiB   [19922944, 19988480)
  float* Psum = (float*)(ws + 19988480);   // 256 KiB  [19988480, 20250624)
  float* qb   = (float*)(ws + 20250624);   // 16 KiB   [20250624, 20267008)
  float* pbv  = (float*)(ws + 20267008);   // 1 KiB
  float* Lsum = (float*)(ws + 20268032);   // 1 KiB
  float* rcb  = (float*)(ws + 20269056);   // 64 KiB   [20269056, 20334592)
  u16*   Mt   = (u16*)(ws + 20971520);     // up to 64 MiB

  cvtsum_kernel<<<1024, 256, 0, stream>>>(x, xbuf, part);
  prep_kernel<<<1042, 256, 0, stream>>>(x, qkv_w, proj_w, qkv_b, proj_b, lunchbox,
                                        wv, pt, Psum, qb, pbv, Lsum);
  gub_rc_kernel<<<64, 256, 0, stream>>>(x, qkv_w, part, qb, pbv, Lsum, Psum, g, rcb);

  size_t mt_off = 20971520;
  int gb = 8;
  while (gb > 1 && mt_off + (size_t)gb * 8388608 > ws_size) gb >>= 1;
  for (int b0 = 0; b0 < 8; b0 += gb) {
    stage1_kernel<<<gb * 64, 256, 0, stream>>>(pt, wv, g, Mt, b0);
    int nblk = gb * 64;
    stage2_kernel<<<nblk, 512, 0, stream>>>(x, xbuf, Mt, rcb, d_out, b0, nblk);
  }
}

// Round 7
// 104.203 us; speedup vs baseline: 2.0478x; 1.2318x over previous
//
#include <hip/hip_runtime.h>
#include <stdint.h>

typedef unsigned short u16;
typedef unsigned int u32;
typedef __attribute__((ext_vector_type(8))) short short8;
typedef __attribute__((ext_vector_type(4))) float f32x4;

#define B_    8
#define N_    4096
#define DIM_  256
#define HD_   2048
#define NQKV_ 4096

__device__ __forceinline__ float bf2f(u16 u) {
  union { u32 u; float f; } v; v.u = ((u32)u) << 16; return v.f;
}
__device__ __forceinline__ u16 f2bf(float f) {
  union { float f; u32 u; } v; v.f = f;
  u32 r = v.u + 0x7fffu + ((v.u >> 16) & 1u);
  return (u16)(r >> 16);
}
__device__ __forceinline__ float ldin(const void* p, size_t i, int isbf) {
  return isbf ? bf2f(((const u16*)p)[i]) : ((const float*)p)[i];
}
__device__ __forceinline__ void load16_to_lds(const u16* gsrc, u16* ldst) {
  auto gp = (const __attribute__((address_space(1))) void*)(uintptr_t)gsrc;
  auto lp = (__attribute__((address_space(3))) void*)(uintptr_t)ldst;
  __builtin_amdgcn_global_load_lds(gp, lp, 16, 0, 0);
}
__device__ __forceinline__ int probe_isbf(const void* x) {
  u32 w = ((const u32*)x)[threadIdx.x & 63];
  int e = (int)((w >> 7) & 0xff);
  unsigned long long m = __ballot(e >= 118 && e <= 130);
  return __popcll(m) >= 32;
}

// ---- x -> bf16 + column-sum partials (x read ONCE) ----
__global__ void cvtsum_kernel(const void* __restrict__ x, u16* __restrict__ xb,
                              float* __restrict__ part) {
  int isbf = probe_isbf(x);
  int b = blockIdx.x >> 7, ch = blockIdx.x & 127, t = threadIdx.x;
  size_t base = ((size_t)b * N_ + (size_t)ch * 32) * DIM_ + t;
  float s = 0.f;
  for (int n = 0; n < 32; ++n) {
    float v = ldin(x, base + (size_t)n * DIM_, isbf);
    xb[base + (size_t)n * DIM_] = f2bf(v);
    s += v;
  }
  part[(b * 128 + ch) * DIM_ + t] = s;
}

// ---- fused prep: cvt_wv | tr_pt | Psum | qb | pbv | Lsum | xsum-final ----
__global__ void prep_kernel(const void* __restrict__ x, const void* __restrict__ qkv_w,
                            const void* __restrict__ proj_w, const void* __restrict__ qkv_b,
                            const void* __restrict__ proj_b, const void* __restrict__ lunchbox,
                            u16* __restrict__ wv, u16* __restrict__ pt,
                            float* __restrict__ Psum, float* __restrict__ qb,
                            float* __restrict__ pbv, float* __restrict__ Lsum,
                            const float* __restrict__ part, float* __restrict__ xsum) {
  int isbf = probe_isbf(x);
  int bid = blockIdx.x, t = threadIdx.x;
  if (bid < 256) {
    size_t i = ((size_t)bid * 256 + t) * 8;
    int k = (int)(i >> 11), e = (int)(i & 2047);
    size_t src = (size_t)k * NQKV_ + HD_ + e;
    short8 o;
#pragma unroll
    for (int j = 0; j < 8; ++j) o[j] = (short)f2bf(ldin(qkv_w, src + j, isbf));
    *(short8*)&wv[i] = o;
  } else if (bid < 768) {
    __shared__ float tile[32][33];
    int bid2 = bid - 256;
    int c0 = (bid2 & 7) * 32, e0 = (bid2 >> 3) * 32;
    int tx = t & 31, ty = t >> 5;
    for (int i = ty; i < 32; i += 8)
      tile[i][tx] = ldin(proj_w, (size_t)(e0 + i) * 256 + c0 + tx, isbf);
    __syncthreads();
    for (int i = ty; i < 32; i += 8)
      pt[(size_t)(c0 + i) * HD_ + e0 + tx] = f2bf(tile[tx][i]);
  } else if (bid < 1024) {
    int d = bid - 768;
    float s = 0.f;
    for (int jj = 0; jj < 8; ++jj) s += ldin(proj_w, (size_t)(jj * 256 + d) * 256 + t, isbf);
    Psum[d * 256 + t] = s;
  } else if (bid < 1040) {
    int i = (bid - 1024) * 256 + t;
    qb[i] = ldin(qkv_b, i, isbf);
  } else if (bid == 1040) {
    pbv[t] = ldin(proj_b, t, isbf);
  } else if (bid == 1041) {
    float s = 0.f;
    for (int r = 0; r < 32; ++r) s += ldin(lunchbox, (size_t)t * 32 + r, isbf);
    Lsum[t] = s;
  } else {
    // xsum-final: b = bid-1042
    int b = bid - 1042;
    float s = 0.f;
    for (int c = 0; c < 128; ++c) s += part[(b * 128 + c) * DIM_ + t];
    xsum[b * DIM_ + t] = s;
  }
}

// ---- gpart[kc][b][hd] = sum_{k in kc*64..+64} xsum[b][k]*Wq[k][hd] ----
__global__ void gpart_kernel(const void* __restrict__ xraw, const void* __restrict__ qkv_w,
                             const float* __restrict__ xsum, float* __restrict__ gpart) {
  int isbf = probe_isbf(xraw);
  int bid = blockIdx.x, t = threadIdx.x;
  int kc = bid & 3, hc = (bid >> 2) & 7, b = bid >> 5;   // 4*8*8 = 256
  __shared__ float xs[64];
  if (t < 64) xs[t] = xsum[b * 256 + kc * 64 + t];
  __syncthreads();
  int hd = hc * 256 + t;
  float s = 0.f;
#pragma unroll 8
  for (int i = 0; i < 64; ++i)
    s += xs[i] * ldin(qkv_w, (size_t)(kc * 64 + i) * NQKV_ + hd, isbf);
  gpart[kc * 16384 + b * HD_ + hd] = s;
}

// ---- gfin: g[b][hd] + rcpart[ds][bh][c] ----
__global__ void gfin_kernel(const float* __restrict__ gpart, const float* __restrict__ qb,
                            const float* __restrict__ Lsum, const float* __restrict__ Psum,
                            float* __restrict__ g, float* __restrict__ rcpart) {
  int bid = blockIdx.x, t = threadIdx.x;
  int ds = bid & 3, bh = bid >> 2;                        // 4*64 = 256
  int b = bh >> 3, h = bh & 7;
  __shared__ float us[64];
  if (t < 64) {
    int d = ds * 64 + t, hd = h * 256 + d;
    float sum = gpart[b * HD_ + hd] + gpart[16384 + b * HD_ + hd] +
                gpart[32768 + b * HD_ + hd] + gpart[49152 + b * HD_ + hd];
    float gg = 0.0625f * (sum + 4096.0f * qb[hd]) * Lsum[d];
    g[b * HD_ + hd] = gg;
    us[t] = gg * qb[HD_ + hd];
  }
  __syncthreads();
  float r = 0.f;
#pragma unroll 8
  for (int i = 0; i < 64; ++i)
    r += us[i] * Psum[(ds * 64 + i) * 256 + t];
  rcpart[ds * 16384 + bh * 256 + t] = r;
}

// ---- stage 1 v2: W'(g-scaled, swizzled) in LDS, reused across 4 jj-tiles ----
__global__ __launch_bounds__(256, 2) void stage1_kernel(
    const u16* __restrict__ pt, const u16* __restrict__ wv,
    const float* __restrict__ g, u16* __restrict__ Mt, int b0) {
  __shared__ alignas(16) char smem[81920];
  u16* Wp = (u16*)smem;
  char* Adb = smem + 65536;
  float* eps = (float*)(smem + 65536);

  int bid = blockIdx.x;
  int c0i = bid & 1, jh = (bid >> 1) & 1, k0i = (bid >> 2) & 1;
  int h = (bid >> 3) & 7, bb = bid >> 6;
  int b = b0 + bb;
  int c0 = c0i * 128, k0 = k0i * 128;
  const int t = threadIdx.x, lane = t & 63, wave = t >> 6;
  const int wr = wave >> 1, wc = wave & 1;
  const int panel = bb * 8 + h;

  {
    const u16* wsrc = wv + (size_t)k0 * HD_ + h * 256;
    const float* gp = g + b * HD_ + h * 256;
#pragma unroll
    for (int it = 0; it < 16; ++it) {
      int idx = it * 256 + t;
      int row = idx >> 5, chunk = idx & 31;
      short8 w8 = *(const short8*)&wsrc[(size_t)row * HD_ + chunk * 8];
      f32x4 g0 = *(const f32x4*)&gp[chunk * 8];
      f32x4 g1 = *(const f32x4*)&gp[chunk * 8 + 4];
      short8 o;
      o[0] = (short)f2bf(bf2f((u16)w8[0]) * g0[0]);
      o[1] = (short)f2bf(bf2f((u16)w8[1]) * g0[1]);
      o[2] = (short)f2bf(bf2f((u16)w8[2]) * g0[2]);
      o[3] = (short)f2bf(bf2f((u16)w8[3]) * g0[3]);
      o[4] = (short)f2bf(bf2f((u16)w8[4]) * g1[0]);
      o[5] = (short)f2bf(bf2f((u16)w8[5]) * g1[1]);
      o[6] = (short)f2bf(bf2f((u16)w8[6]) * g1[2]);
      o[7] = (short)f2bf(bf2f((u16)w8[7]) * g1[3]);
      *(short8*)&Wp[row * 256 + ((chunk ^ (row & 7)) * 8)] = o;
    }
  }
  __syncthreads();

#define S1_STAGE(jj, ks, bi)                                                          \
  {                                                                                   \
    _Pragma("unroll") for (int it = 0; it < 2; ++it) {                                \
      int idx = it * 256 + t, row = idx >> 2, slot = idx & 3;                         \
      load16_to_lds(pt + (size_t)(c0 + row) * HD_ + (jj) * 256 + (ks) * 32 +          \
                        ((slot ^ (row & 3)) * 8),                                     \
                    (u16*)(Adb + (bi) * 8192) + idx * 8);                             \
    }                                                                                 \
  }

  for (int jc = 0; jc < 4; ++jc) {
    int jj = jh * 4 + jc;
    f32x4 acc[4][4] = {};
    S1_STAGE(jj, 0, 0);
    __syncthreads();
    int cur = 0;
    for (int ks = 0; ks < 8; ++ks) {
      if (ks < 7) S1_STAGE(jj, ks + 1, cur ^ 1);
      const u16* lA = (const u16*)(Adb + cur * 8192);
      short8 af[4], bfr[4];
      const int ar = wr * 64 + (lane & 15), bc = wc * 64 + (lane & 15);
#pragma unroll
      for (int mi = 0; mi < 4; ++mi) {
        int row = ar + mi * 16;
        af[mi] = *(const short8*)&lA[row * 32 + (((lane >> 4) ^ (row & 3)) * 8)];
      }
#pragma unroll
      for (int ni = 0; ni < 4; ++ni) {
        int kl = bc + ni * 16;
        int chunk = ks * 4 + (lane >> 4);
        bfr[ni] = *(const short8*)&Wp[kl * 256 + ((chunk ^ (kl & 7)) * 8)];
      }
#pragma unroll
      for (int mi = 0; mi < 4; ++mi)
#pragma unroll
        for (int ni = 0; ni < 4; ++ni)
          acc[mi][ni] = __builtin_amdgcn_mfma_f32_16x16x32_bf16(af[mi], bfr[ni], acc[mi][ni], 0, 0, 0);
      __syncthreads();
      cur ^= 1;
    }
    const int rl = t >> 3, cc = (t & 7) * 16;
#pragma unroll
    for (int mi = 0; mi < 4; ++mi) {
      __syncthreads();
#pragma unroll
      for (int ni = 0; ni < 4; ++ni) {
        f32x4 v = acc[mi][ni];
        int re = wr * 16 + (lane >> 4) * 4, ce = wc * 64 + ni * 16 + (lane & 15);
        eps[(re + 0) * 128 + ce] = v[0];
        eps[(re + 1) * 128 + ce] = v[1];
        eps[(re + 2) * 128 + ce] = v[2];
        eps[(re + 3) * 128 + ce] = v[3];
      }
      __syncthreads();
      int cg = c0 + (rl >> 4) * 64 + mi * 16 + (rl & 15);
      alignas(16) u16 pk[16];
#pragma unroll
      for (int j = 0; j < 16; ++j) pk[j] = f2bf(eps[rl * 128 + cc + j]);
      u16* dst = Mt + (size_t)panel * 524288 + (size_t)cg * HD_ + jj * 256 + k0 + cc;
      *(short8*)dst = *(short8*)pk;
      *(short8*)(dst + 8) = *(short8*)(pk + 8);
    }
    __syncthreads();
  }
}

// ---- stage 2 v2: in-block split-K, 512 thr; rc finalization folded in ----
__global__ __launch_bounds__(512, 4) void stage2_kernel(
    const void* __restrict__ xraw, const u16* __restrict__ xb, const u16* __restrict__ Mt,
    const float* __restrict__ rcpart, const float* __restrict__ pbv,
    void* __restrict__ outv, int b0, int nblk) {
  __shared__ alignas(16) char smem[65536];
  float* eps = (float*)smem;

  int bid = blockIdx.x;
  int sid = (bid & 7) * (nblk >> 3) + (bid >> 3);
  int ct = sid & 1, rt = (sid >> 1) & 3, h = (sid >> 3) & 7, bb = sid >> 6;
  int b = b0 + bb;
  int nn0 = rt * 128, c0 = ct * 128;
  const int panel = bb * 8 + h;
  const u16* Abase = xb + (size_t)b * 1048576 + (size_t)nn0 * HD_;
  const u16* Bbase = Mt + (size_t)panel * 524288 + (size_t)c0 * HD_;

  const int t = threadIdx.x;
  const int grp = t >> 8, tt = t & 255;
  const int lane = tt & 63, wave = tt >> 6;
  const int wr = wave >> 1, wc = wave & 1;
  char* mybuf = smem + grp * 32768;

  f32x4 acc[4][4] = {};

#define S2_STAGE(i, bi)                                                            \
  {                                                                                \
    int kcol = ((i) * 2 + grp) * 32;                                               \
    _Pragma("unroll") for (int it = 0; it < 2; ++it) {                             \
      int idx = it * 256 + tt, row = idx >> 2, slot = idx & 3;                     \
      int sc = kcol + ((slot ^ (row & 3)) * 8);                                    \
      load16_to_lds(Abase + (size_t)row * HD_ + sc,                                \
                    (u16*)(mybuf + (bi) * 16384) + idx * 8);                       \
      load16_to_lds(Bbase + (size_t)row * HD_ + sc,                                \
                    (u16*)(mybuf + (bi) * 16384 + 8192) + idx * 8);                \
    }                                                                              \
  }

  S2_STAGE(0, 0);
  __syncthreads();
  int cur = 0;
  for (int i = 0; i < 32; ++i) {
    if (i < 31) S2_STAGE(i + 1, cur ^ 1);
    const u16* lA = (const u16*)(mybuf + cur * 16384);
    const u16* lB = lA + 4096;
    short8 af[4], bfr[4];
    const int ar = wr * 64 + (lane & 15), bc = wc * 64 + (lane & 15);
#pragma unroll
    for (int mi = 0; mi < 4; ++mi) {
      int row = ar + mi * 16;
      af[mi] = *(const short8*)&lA[row * 32 + (((lane >> 4) ^ (row & 3)) * 8)];
    }
#pragma unroll
    for (int ni = 0; ni < 4; ++ni) {
      int row = bc + ni * 16;
      bfr[ni] = *(const short8*)&lB[row * 32 + (((lane >> 4) ^ (row & 3)) * 8)];
    }
#pragma unroll
    for (int mi = 0; mi < 4; ++mi)
#pragma unroll
      for (int ni = 0; ni < 4; ++ni)
        acc[mi][ni] = __builtin_amdgcn_mfma_f32_16x16x32_bf16(af[mi], bfr[ni], acc[mi][ni], 0, 0, 0);
    __syncthreads();
    cur ^= 1;
  }

  int isbf = probe_isbf(xraw);
  const int rl = t >> 4, cc = (t & 15) * 8;
  float rc[8];
  {
    const float* rp = rcpart + (size_t)(b * 8 + h) * 256 + c0 + cc;
    const float* pb = pbv + c0 + cc;
#pragma unroll
    for (int j = 0; j < 8; ++j)
      rc[j] = rp[j] + rp[16384 + j] + rp[32768 + j] + rp[49152 + j] + pb[j];
  }
#pragma unroll
  for (int mi = 0; mi < 4; ++mi) {
    __syncthreads();
    if (grp == 0) {
#pragma unroll
      for (int ni = 0; ni < 4; ++ni) {
        f32x4 v = acc[mi][ni];
        int re = wr * 16 + (lane >> 4) * 4, ce = wc * 64 + ni * 16 + (lane & 15);
        eps[(re + 0) * 128 + ce] = v[0];
        eps[(re + 1) * 128 + ce] = v[1];
        eps[(re + 2) * 128 + ce] = v[2];
        eps[(re + 3) * 128 + ce] = v[3];
      }
    }
    __syncthreads();
    if (grp == 1) {
#pragma unroll
      for (int ni = 0; ni < 4; ++ni) {
        f32x4 v = acc[mi][ni];
        int re = wr * 16 + (lane >> 4) * 4, ce = wc * 64 + ni * 16 + (lane & 15);
        eps[(re + 0) * 128 + ce] += v[0];
        eps[(re + 1) * 128 + ce] += v[1];
        eps[(re + 2) * 128 + ce] += v[2];
        eps[(re + 3) * 128 + ce] += v[3];
      }
    }
    __syncthreads();
    int grow = b * N_ + h * 512 + nn0 + (rl >> 4) * 64 + mi * 16 + (rl & 15);
    if (isbf) {
      alignas(16) u16 pk[8];
#pragma unroll
      for (int j = 0; j < 8; ++j) pk[j] = f2bf(eps[rl * 128 + cc + j] + rc[j]);
      *(short8*)((u16*)outv + (size_t)grow * 256 + c0 + cc) = *(short8*)pk;
    } else {
      float* op = (float*)outv + (size_t)grow * 256 + c0 + cc;
      f32x4 o0, o1;
      o0[0] = eps[rl * 128 + cc + 0] + rc[0];
      o0[1] = eps[rl * 128 + cc + 1] + rc[1];
      o0[2] = eps[rl * 128 + cc + 2] + rc[2];
      o0[3] = eps[rl * 128 + cc + 3] + rc[3];
      o1[0] = eps[rl * 128 + cc + 4] + rc[4];
      o1[1] = eps[rl * 128 + cc + 5] + rc[5];
      o1[2] = eps[rl * 128 + cc + 6] + rc[6];
      o1[3] = eps[rl * 128 + cc + 7] + rc[7];
      ((f32x4*)op)[0] = o0;
      ((f32x4*)op)[1] = o1;
    }
  }
}

extern "C" void kernel_launch(void* const* d_in, const int* in_sizes, int n_in,
                              void* d_out, int out_size, void* d_ws, size_t ws_size,
                              hipStream_t stream) {
  const void* x        = d_in[0];
  const void* qkv_w    = d_in[1];
  const void* qkv_b    = d_in[2];
  const void* lunchbox = d_in[3];
  const void* proj_w   = d_in[4];
  const void* proj_b   = d_in[5];
  char* ws = (char*)d_ws;

  u16*   xbuf   = (u16*)(ws + 0);            // 16 MiB   [0, 16777216)
  u16*   wv     = (u16*)(ws + 16777216);     // 1 MiB
  u16*   pt     = (u16*)(ws + 17825792);     // 1 MiB
  float* part   = (float*)(ws + 18874368);   // 1 MiB    [18874368, 19922944)
  float* xsum   = (float*)(ws + 19922944);   // 8 KiB
  float* g      = (float*)(ws + 19931136);   // 64 KiB
  float* gpart  = (float*)(ws + 19996672);   // 256 KiB  [19996672, 20258816)
  float* rcpart = (float*)(ws + 20258816);   // 256 KiB  [20258816, 20520960)
  float* Psum   = (float*)(ws + 20520960);   // 256 KiB  [20520960, 20783104)
  float* qb     = (float*)(ws + 20783104);   // 16 KiB
  float* pbv    = (float*)(ws + 20799488);   // 1 KiB
  float* Lsum   = (float*)(ws + 20800512);   // 1 KiB
  u16*   Mt     = (u16*)(ws + 20971520);     // up to 64 MiB

  cvtsum_kernel<<<1024, 256, 0, stream>>>(x, xbuf, part);
  prep_kernel<<<1050, 256, 0, stream>>>(x, qkv_w, proj_w, qkv_b, proj_b, lunchbox,
                                        wv, pt, Psum, qb, pbv, Lsum, part, xsum);
  gpart_kernel<<<256, 256, 0, stream>>>(x, qkv_w, xsum, gpart);
  gfin_kernel<<<256, 256, 0, stream>>>(gpart, qb, Lsum, Psum, g, rcpart);

  size_t mt_off = 20971520;
  int gb = 8;
  while (gb > 1 && mt_off + (size_t)gb * 8388608 > ws_size) gb >>= 1;
  for (int b0 = 0; b0 < 8; b0 += gb) {
    stage1_kernel<<<gb * 64, 256, 0, stream>>>(pt, wv, g, Mt, b0);
    int nblk = gb * 64;
    stage2_kernel<<<nblk, 512, 0, stream>>>(x, xbuf, Mt, rcpart, pbv, d_out, b0, nblk);
  }
}